// Round 1
// baseline (1210.348 us; speedup 1.0000x reference)
//
#include <hip/hip_runtime.h>
#include <cmath>

#define SRATE 16000
#define WIN   400
#define HOP   160
#define NFFT  512
#define NBIN  257          // NFFT/2+1
#define NMELS 40
#define NMFCC 13
#define BB    64
#define LL    160000
#define NF    998          // (L-WIN)/HOP + 1

#define PI_D 3.14159265358979323846

// workspace layout (floats)
#define WS_WINDOW 0
#define WS_FBANK  (WS_WINDOW + WIN)              // 400
#define WS_DCT    (WS_FBANK + NMELS * NBIN)      // 400 + 10280
#define WS_TOTAL  (WS_DCT + NMELS * NMELS)       // 12280 floats

// ---------------------------------------------------------------------------
// Init kernel: recompute the constant tables every launch (ws is re-poisoned).
// All math in double to mirror the numpy reference construction exactly.
// ---------------------------------------------------------------------------
__global__ void init_tables(float* __restrict__ ws) {
    __shared__ double bins[NMELS + 2];
    const int tid = threadIdx.x;

    // Hamming window (periodic): 0.54 - 0.46*cos(2*pi*i/WIN)
    for (int i = tid; i < WIN; i += blockDim.x) {
        double w = 0.54 - 0.46 * cos(2.0 * PI_D * (double)i / (double)WIN);
        ws[WS_WINDOW + i] = (float)w;
    }

    // DCT-II ortho matrix [NMELS x NMELS], row k, col n
    for (int i = tid; i < NMELS * NMELS; i += blockDim.x) {
        int k = i / NMELS, n = i % NMELS;
        double c = cos(PI_D * (double)k * (2.0 * n + 1.0) / (2.0 * NMELS));
        double scale = (k == 0) ? sqrt(1.0 / NMELS) : sqrt(2.0 / NMELS);
        ws[WS_DCT + i] = (float)(scale * c);
    }

    // mel bin edges (float64, matching np.linspace semantics incl. endpoint)
    if (tid < NMELS + 2) {
        double high_mel = 2595.0 * log10(1.0 + ((double)SRATE / 2.0) / 700.0);
        double step = high_mel / (double)(NMELS + 1);
        double mel = (tid == NMELS + 1) ? high_mel : (double)tid * step;
        double hz = 700.0 * (pow(10.0, mel / 2595.0) - 1.0);
        bins[tid] = floor((double)(NFFT + 1) * hz / (double)SRATE);
    }
    __syncthreads();

    // triangular filterbank rows [NMELS x NBIN]
    for (int m = tid; m < NMELS; m += blockDim.x) {
        int f_lo = (int)bins[m], f_c = (int)bins[m + 1], f_hi = (int)bins[m + 2];
        float* row = ws + WS_FBANK + m * NBIN;
        for (int k = 0; k < NBIN; k++) row[k] = 0.0f;
        for (int k = f_lo; k < f_c; k++)
            row[k] = (float)((double)(k - f_lo) / (double)(f_c - f_lo));
        for (int k = f_c; k < f_hi; k++)
            row[k] = (float)((double)(f_hi - k) / (double)(f_hi - f_c));
    }
}

// ---------------------------------------------------------------------------
// Main kernel: one block per (batch, frame).
// ---------------------------------------------------------------------------
#define NTHREADS 256

__global__ __launch_bounds__(NTHREADS) void mfcc_kernel(
    const float* __restrict__ x, const float* __restrict__ ws,
    float* __restrict__ out) {

    __shared__ float s[NFFT];             // windowed frame, zero-padded
    __shared__ float mag[NBIN];           // magnitude spectrum
    __shared__ float partial[6][NMELS];   // mel partial sums
    __shared__ float lm[NMELS];
    __shared__ float cep[NMELS];
    __shared__ float d1[NMELS];
    __shared__ float d2[NMELS];

    const int bx = blockIdx.x;
    const int b = bx / NF;
    const int f = bx - b * NF;
    const int tid = threadIdx.x;
    const float* xb = x + (size_t)b * LL;
    const int start = f * HOP;

    // ---- stage frame: pre-emphasis + hamming window, zero-pad to NFFT ----
    for (int i = tid; i < NFFT; i += NTHREADS) {
        float v = 0.0f;
        if (i < WIN) {
            int g = start + i;
            float cur = xb[g];
            float y = (g > 0) ? (cur - 0.97f * xb[g - 1]) : cur;
            v = y * ws[WS_WINDOW + i];
        }
        s[i] = v;
    }
    __syncthreads();

    // ---- DFT bin k = tid (0..255): rotation recurrence, re-seeded /50 ----
    {
        const int k = tid;
        float re = 0.0f, im = 0.0f;
        float cs, ss;  // step twiddle e^{-2*pi*i*k/512}
        sincosf(-2.0f * (float)PI_D * (float)k / 512.0f, &ss, &cs);
        for (int n0 = 0; n0 < WIN; n0 += 50) {
            int m = (k * n0) & (NFFT - 1);
            float c, d;
            sincosf(-2.0f * (float)PI_D * (float)m / 512.0f, &d, &c);
            #pragma unroll 10
            for (int j = 0; j < 50; j++) {
                float v = s[n0 + j];      // LDS broadcast (same addr all lanes)
                re = fmaf(v, c, re);
                im = fmaf(v, d, im);
                float c2 = c * cs - d * ss;
                d = c * ss + d * cs;
                c = c2;
            }
        }
        mag[k] = sqrtf(re * re + im * im);
    }

    // ---- bin 256 (Nyquist): alternating sum, wave 0 shuffle-reduce ----
    if (tid < 64) {
        float a = 0.0f;
        for (int n = tid; n < WIN; n += 64) a += s[n];
        a *= (tid & 1) ? -1.0f : 1.0f;    // parity of n == parity of lane
        #pragma unroll
        for (int off = 32; off > 0; off >>= 1) a += __shfl_down(a, off, 64);
        if (tid == 0) mag[256] = fabsf(a);
    }
    __syncthreads();

    // ---- mel filterbank + log: 6-way split of the k range ----
    {
        const int p = tid / NMELS;        // 0..5 active
        const int m = tid - p * NMELS;
        if (p < 6) {
            int k0 = 43 * p;
            int k1 = (k0 + 43 < NBIN) ? (k0 + 43) : NBIN;
            const float* row = ws + WS_FBANK + m * NBIN;
            float acc = 0.0f;
            for (int k = k0; k < k1; k++) acc = fmaf(row[k], mag[k], acc);
            partial[p][m] = acc;
        }
    }
    __syncthreads();

    if (tid < NMELS) {
        float acc = 1e-20f;
        #pragma unroll
        for (int p = 0; p < 6; p++) acc += partial[p][tid];
        lm[tid] = logf(acc);
    }
    __syncthreads();

    // ---- DCT-II (ortho): cep[c] = sum_m dct[c][m] * lm[m] ----
    if (tid < NMELS) {
        const float* drow = ws + WS_DCT + tid * NMELS;
        float acc = 0.0f;
        #pragma unroll
        for (int m = 0; m < NMELS; m++) acc = fmaf(drow[m], lm[m], acc);
        cep[tid] = acc;
    }
    __syncthreads();

    // ---- deltas along coefficient axis ----
    if (tid < NMELS)
        d1[tid] = (tid >= 1 && tid <= NMELS - 2)
                      ? 0.5f * (cep[tid + 1] - cep[tid - 1]) : 0.0f;
    __syncthreads();
    if (tid < NMELS)
        d2[tid] = (tid >= 1 && tid <= NMELS - 2)
                      ? 0.5f * (d1[tid + 1] - d1[tid - 1]) : 0.0f;
    __syncthreads();

    // ---- write [mfcc[:13], d1[:13], d2[:13]] ----
    if (tid < 3 * NMFCC) {
        float v;
        if (tid < NMFCC)            v = cep[tid];
        else if (tid < 2 * NMFCC)   v = d1[tid - NMFCC];
        else                        v = d2[tid - 2 * NMFCC];
        out[(size_t)(b * NF + f) * (3 * NMFCC) + tid] = v;
    }
}

// ---------------------------------------------------------------------------
extern "C" void kernel_launch(void* const* d_in, const int* in_sizes, int n_in,
                              void* d_out, int out_size, void* d_ws, size_t ws_size,
                              hipStream_t stream) {
    const float* x = (const float*)d_in[0];
    float* ws = (float*)d_ws;
    float* out = (float*)d_out;

    init_tables<<<1, 256, 0, stream>>>(ws);
    mfcc_kernel<<<BB * NF, NTHREADS, 0, stream>>>(x, ws, out);
}

// Round 2
// 1064.187 us; speedup vs baseline: 1.1373x; 1.1373x over previous
//
#include <hip/hip_runtime.h>
#include <cmath>

#define SRATE 16000
#define WIN   400
#define HOP   160
#define NFFT  512
#define NBIN  257          // NFFT/2+1
#define NMELS 40
#define NMFCC 13
#define BB    64
#define LL    160000
#define NF    998          // (L-WIN)/HOP + 1

#define PI_D 3.14159265358979323846

// workspace layout (floats)
#define WS_WINDOW 0
#define WS_FBANK  (WS_WINDOW + WIN)              // 400
#define WS_DCT    (WS_FBANK + NMELS * NBIN)      // 400 + 10280
#define WS_TW256  (WS_DCT + NMELS * NMELS)       // +1600  (128 re, 128 im)
#define WS_TW512  (WS_TW256 + 256)               // +256   (257 re, 257 im)
#define WS_TOTAL  (WS_TW512 + 514)

// ---------------------------------------------------------------------------
// Init kernel: recompute constant tables every launch (ws is re-poisoned).
// All math in double to mirror the numpy reference construction exactly.
// ---------------------------------------------------------------------------
__global__ void init_tables(float* __restrict__ ws) {
    __shared__ double bins[NMELS + 2];
    const int tid = threadIdx.x;

    // Hamming window (periodic)
    for (int i = tid; i < WIN; i += blockDim.x) {
        double w = 0.54 - 0.46 * cos(2.0 * PI_D * (double)i / (double)WIN);
        ws[WS_WINDOW + i] = (float)w;
    }

    // DCT-II ortho matrix [NMELS x NMELS]
    for (int i = tid; i < NMELS * NMELS; i += blockDim.x) {
        int k = i / NMELS, n = i % NMELS;
        double c = cos(PI_D * (double)k * (2.0 * n + 1.0) / (2.0 * NMELS));
        double scale = (k == 0) ? sqrt(1.0 / NMELS) : sqrt(2.0 / NMELS);
        ws[WS_DCT + i] = (float)(scale * c);
    }

    // FFT-256 twiddles: e^{-2*pi*i*k/256}, k=0..127
    for (int i = tid; i < 128; i += blockDim.x) {
        double ang = -2.0 * PI_D * (double)i / 256.0;
        ws[WS_TW256 + i]       = (float)cos(ang);
        ws[WS_TW256 + 128 + i] = (float)sin(ang);
    }
    // rfft untangle twiddles: e^{-2*pi*i*k/512}, k=0..256
    for (int i = tid; i < NBIN; i += blockDim.x) {
        double ang = 2.0 * PI_D * (double)i / 512.0;
        ws[WS_TW512 + i]        = (float)cos(ang);
        ws[WS_TW512 + NBIN + i] = (float)(-sin(ang));
    }

    // mel bin edges
    if (tid < NMELS + 2) {
        double high_mel = 2595.0 * log10(1.0 + ((double)SRATE / 2.0) / 700.0);
        double step = high_mel / (double)(NMELS + 1);
        double mel = (tid == NMELS + 1) ? high_mel : (double)tid * step;
        double hz = 700.0 * (pow(10.0, mel / 2595.0) - 1.0);
        bins[tid] = floor((double)(NFFT + 1) * hz / (double)SRATE);
    }
    __syncthreads();

    // triangular filterbank rows [NMELS x NBIN]
    for (int m = tid; m < NMELS; m += blockDim.x) {
        int f_lo = (int)bins[m], f_c = (int)bins[m + 1], f_hi = (int)bins[m + 2];
        float* row = ws + WS_FBANK + m * NBIN;
        for (int k = 0; k < NBIN; k++) row[k] = 0.0f;
        for (int k = f_lo; k < f_c; k++)
            row[k] = (float)((double)(k - f_lo) / (double)(f_c - f_lo));
        for (int k = f_c; k < f_hi; k++)
            row[k] = (float)((double)(f_hi - k) / (double)(f_hi - f_c));
    }
}

// ---------------------------------------------------------------------------
// Main kernel: one block per (batch, frame). 512-pt real FFT via 256-pt
// complex Stockham FFT (even/odd packing) + untangle.
// ---------------------------------------------------------------------------
#define NTHREADS 256

__global__ __launch_bounds__(NTHREADS) void mfcc_kernel(
    const float* __restrict__ x, const float* __restrict__ ws,
    float* __restrict__ out) {

    __shared__ float Are[256], Aim[256];   // ping
    __shared__ float Bre[256], Bim[256];   // pong
    __shared__ float twr[128], twi[128];   // FFT-256 twiddles
    __shared__ float mag[NBIN];
    __shared__ float partial[6][NMELS];
    __shared__ float lm[NMELS];
    __shared__ float cep[NMELS];
    __shared__ float d1[NMELS];
    __shared__ float d2[NMELS];

    const int bx = blockIdx.x;
    const int b = bx / NF;
    const int f = bx - b * NF;
    const int tid = threadIdx.x;
    const float* xb = x + (size_t)b * LL;
    const int start = f * HOP;

    // ---- twiddle tables to LDS ----
    if (tid < 128) {
        twr[tid] = ws[WS_TW256 + tid];
        twi[tid] = ws[WS_TW256 + 128 + tid];
    }

    // ---- pack: z[n] = s[2n] + i*s[2n+1], pre-emphasis + hamming fused ----
    {
        float zr = 0.0f, zi = 0.0f;
        if (tid < WIN / 2) {               // 200 pairs
            int g = start + 2 * tid;
            float x0 = xb[g];
            float x1 = xb[g + 1];
            float y0 = (g > 0) ? (x0 - 0.97f * xb[g - 1]) : x0;
            float y1 = x1 - 0.97f * x0;
            zr = y0 * ws[WS_WINDOW + 2 * tid];
            zi = y1 * ws[WS_WINDOW + 2 * tid + 1];
        }
        Are[tid] = zr; Aim[tid] = zi;
    }
    __syncthreads();

    // ---- 8 Stockham radix-2 stages (output-centric, ping-pong) ----
#define STAGE(s, IR, II, OR, OI)                                      \
    do {                                                              \
        const int Ns = 1 << (s);                                      \
        int m_ = tid & (2 * Ns - 1);                                  \
        int mm_ = m_ & (Ns - 1);                                      \
        int j_ = ((tid >> ((s) + 1)) << (s)) | mm_;                   \
        float ar = IR[j_], ai = II[j_];                               \
        float br = IR[j_ + 128], bi = II[j_ + 128];                   \
        float wr_ = twr[mm_ << (7 - (s))], wi_ = twi[mm_ << (7 - (s))]; \
        float tr = wr_ * br - wi_ * bi;                               \
        float ti = wr_ * bi + wi_ * br;                               \
        bool up = (m_ < Ns);                                          \
        OR[tid] = up ? (ar + tr) : (ar - tr);                         \
        OI[tid] = up ? (ai + ti) : (ai - ti);                         \
        __syncthreads();                                              \
    } while (0)

    STAGE(0, Are, Aim, Bre, Bim);
    STAGE(1, Bre, Bim, Are, Aim);
    STAGE(2, Are, Aim, Bre, Bim);
    STAGE(3, Bre, Bim, Are, Aim);
    STAGE(4, Are, Aim, Bre, Bim);
    STAGE(5, Bre, Bim, Are, Aim);
    STAGE(6, Are, Aim, Bre, Bim);
    STAGE(7, Bre, Bim, Are, Aim);   // result (natural order) in A
#undef STAGE

    // ---- untangle to rfft magnitude: X[k], k = tid ----
    {
        const int k = tid;
        float a = Are[k],  bI = Aim[k];
        int k2 = (256 - k) & 255;
        float c = Are[k2], dI = Aim[k2];
        float Pr = a + c,  Pi = bI - dI;
        float Qr = a - c,  Qi = bI + dI;
        float wr_ = ws[WS_TW512 + k];
        float wi_ = ws[WS_TW512 + NBIN + k];
        float Xr = 0.5f * (Pr + wi_ * Qr + wr_ * Qi);
        float Xi = 0.5f * (Pi + wi_ * Qi - wr_ * Qr);
        mag[k] = sqrtf(Xr * Xr + Xi * Xi);
        if (k == 0) mag[256] = fabsf(a - bI);   // Nyquist: ReZ0 - ImZ0
    }
    __syncthreads();

    // ---- mel filterbank + log: 6-way split of k range ----
    {
        const int p = tid / NMELS;
        const int m = tid - p * NMELS;
        if (p < 6) {
            int k0 = 43 * p;
            int k1 = (k0 + 43 < NBIN) ? (k0 + 43) : NBIN;
            const float* row = ws + WS_FBANK + m * NBIN;
            float acc = 0.0f;
            for (int k = k0; k < k1; k++) acc = fmaf(row[k], mag[k], acc);
            partial[p][m] = acc;
        }
    }
    __syncthreads();

    if (tid < NMELS) {
        float acc = 1e-20f;
        #pragma unroll
        for (int p = 0; p < 6; p++) acc += partial[p][tid];
        lm[tid] = logf(acc);
    }
    __syncthreads();

    // ---- DCT-II (ortho) ----
    if (tid < NMELS) {
        const float* drow = ws + WS_DCT + tid * NMELS;
        float acc = 0.0f;
        #pragma unroll
        for (int m = 0; m < NMELS; m++) acc = fmaf(drow[m], lm[m], acc);
        cep[tid] = acc;
    }
    __syncthreads();

    // ---- deltas along coefficient axis ----
    if (tid < NMELS)
        d1[tid] = (tid >= 1 && tid <= NMELS - 2)
                      ? 0.5f * (cep[tid + 1] - cep[tid - 1]) : 0.0f;
    __syncthreads();
    if (tid < NMELS)
        d2[tid] = (tid >= 1 && tid <= NMELS - 2)
                      ? 0.5f * (d1[tid + 1] - d1[tid - 1]) : 0.0f;
    __syncthreads();

    // ---- write [mfcc[:13], d1[:13], d2[:13]] ----
    if (tid < 3 * NMFCC) {
        float v;
        if (tid < NMFCC)            v = cep[tid];
        else if (tid < 2 * NMFCC)   v = d1[tid - NMFCC];
        else                        v = d2[tid - 2 * NMFCC];
        out[(size_t)(b * NF + f) * (3 * NMFCC) + tid] = v;
    }
}

// ---------------------------------------------------------------------------
extern "C" void kernel_launch(void* const* d_in, const int* in_sizes, int n_in,
                              void* d_out, int out_size, void* d_ws, size_t ws_size,
                              hipStream_t stream) {
    const float* x = (const float*)d_in[0];
    float* ws = (float*)d_ws;
    float* out = (float*)d_out;

    init_tables<<<1, 256, 0, stream>>>(ws);
    mfcc_kernel<<<BB * NF, NTHREADS, 0, stream>>>(x, ws, out);
}

// Round 3
// 344.592 us; speedup vs baseline: 3.5124x; 3.0883x over previous
//
#include <hip/hip_runtime.h>
#include <cmath>

#define SRATE 16000
#define WIN   400
#define HOP   160
#define NFFT  512
#define NBIN  257          // NFFT/2+1
#define NMELS 40
#define NMFCC 13
#define BB    64
#define LL    160000
#define NF    998          // (L-WIN)/HOP + 1

#define PI_D 3.14159265358979323846

// workspace layout (floats) — all float4-aligned where needed
#define WS_WINDOW 0                    // 400
#define WS_TW512C 400                  // 257 (pad to 260)
#define WS_TW512S 660                  // 257 (pad to 260)
#define WS_STW    920                  // 6 stages x (128 cos + 128 sin) = 1536
#define WS_MELSC  2456                 // 256 x float4 = 1024
#define WS_MT     3480                 // 40 x 39 = 1560
#define WS_TOTAL  (WS_MT + 1560)       // 5040 floats

// ---------------------------------------------------------------------------
// Init kernel: recompute constant tables every launch (ws is re-poisoned).
// All math in double to mirror the numpy reference construction exactly.
// ---------------------------------------------------------------------------
__global__ void init_tables(float* __restrict__ ws) {
    __shared__ double bins[NMELS + 2];
    const int tid = threadIdx.x;

    // Hamming window (periodic)
    for (int i = tid; i < WIN; i += 256)
        ws[WS_WINDOW + i] = (float)(0.54 - 0.46 * cos(2.0 * PI_D * (double)i / (double)WIN));

    // rfft untangle twiddles: cos(2*pi*k/512), -sin(2*pi*k/512)
    for (int i = tid; i < NBIN; i += 256) {
        double ang = 2.0 * PI_D * (double)i / 512.0;
        ws[WS_TW512C + i] = (float)cos(ang);
        ws[WS_TW512S + i] = (float)(-sin(ang));
    }

    // per-stage expanded FFT-256 twiddles, stages s=2..7, indexed by butterfly j
    for (int i = tid; i < 6 * 128; i += 256) {
        int si = i >> 7, j = i & 127;
        int s = si + 2, Ns = 1 << s;
        int idx = (j & (Ns - 1)) << (7 - s);
        double ang = -2.0 * PI_D * (double)idx / 256.0;
        ws[WS_STW + si * 256 + j]       = (float)cos(ang);
        ws[WS_STW + si * 256 + 128 + j] = (float)sin(ang);
    }

    // mel bin edges
    if (tid < NMELS + 2) {
        double high_mel = 2595.0 * log10(1.0 + ((double)SRATE / 2.0) / 700.0);
        double step = high_mel / (double)(NMELS + 1);
        double mel = (tid == NMELS + 1) ? high_mel : (double)tid * step;
        double hz = 700.0 * (pow(10.0, mel / 2595.0) - 1.0);
        bins[tid] = floor((double)(NFFT + 1) * hz / (double)SRATE);
    }
    __syncthreads();

    // per-k mel scatter table: k belongs to rising edge of filter r1 and
    // falling edge of filter r1-1 (r1 in 0..40; r1==40 => only falling of 39).
    for (int k = tid; k < 256; k += 256) {
        int r1 = 0;
        while (r1 < NMELS + 1 &&
               !((double)k >= bins[r1] && (double)k < bins[r1 + 1])) r1++;
        if (r1 > NMELS) r1 = NMELS;  // safety clamp (unreachable)
        double lo = bins[r1], hi = bins[r1 + 1];
        double den = (hi > lo) ? (hi - lo) : 1.0;
        ws[WS_MELSC + 4 * k + 0] = (float)(((double)k - lo) / den);  // w_rise -> row r1
        ws[WS_MELSC + 4 * k + 1] = (float)((hi - (double)k) / den);  // w_fall -> row r1-1
        ws[WS_MELSC + 4 * k + 2] = (float)r1;
        ws[WS_MELSC + 4 * k + 3] = 0.0f;
    }

    // fused DCT + delta matrix, stored row-per-n transposed: MT[n*39 + i]
    for (int t = tid; t < 40 * 39; t += 256) {
        int n = t / 39, i = t % 39;
        auto dctf = [&](int c) -> double {
            if (c < 0 || c > 39) return 0.0;
            double sc = (c == 0) ? sqrt(1.0 / 40.0) : sqrt(2.0 / 40.0);
            return sc * cos(PI_D * (double)c * (2.0 * n + 1.0) / 80.0);
        };
        auto d1f = [&](int c) -> double {
            if (c < 1 || c > 38) return 0.0;
            return 0.5 * (dctf(c + 1) - dctf(c - 1));
        };
        double v;
        if (i < 13)       v = dctf(i);
        else if (i < 26)  v = d1f(i - 13);
        else { int c = i - 26; v = (c >= 1 && c <= 38) ? 0.5 * (d1f(c + 1) - d1f(c - 1)) : 0.0; }
        ws[WS_MT + t] = (float)v;
    }
}

// ---------------------------------------------------------------------------
// Main kernel: one WAVE per frame, 4 frames per block, no __syncthreads.
// ---------------------------------------------------------------------------
#define NTHREADS 256

// Stockham radix-2 stage for s>=2, vectorized: lane handles outputs 4l..4l+3
#define STAGEV(S, IR, II, OR_, OI_, TWOFS)                                   \
    {                                                                        \
        const int Ns = 1 << (S);                                             \
        int jb = ((l >> ((S) - 1)) << (S)) + ((4 * l) & (Ns - 1));           \
        float4 ar = *(const float4*)((IR) + jb);                             \
        float4 ai = *(const float4*)((II) + jb);                             \
        float4 br = *(const float4*)((IR) + jb + 128);                       \
        float4 bi = *(const float4*)((II) + jb + 128);                       \
        const float* twc = ws + (TWOFS);                                     \
        float4 wr = *(const float4*)(twc + jb);                              \
        float4 wi = *(const float4*)(twc + 128 + jb);                        \
        float sg = (((4 * l) & (2 * Ns - 1)) < Ns) ? 1.0f : -1.0f;           \
        float4 orr, oii;                                                     \
        orr.x = fmaf(sg, wr.x * br.x - wi.x * bi.x, ar.x);                   \
        oii.x = fmaf(sg, wr.x * bi.x + wi.x * br.x, ai.x);                   \
        orr.y = fmaf(sg, wr.y * br.y - wi.y * bi.y, ar.y);                   \
        oii.y = fmaf(sg, wr.y * bi.y + wi.y * br.y, ai.y);                   \
        orr.z = fmaf(sg, wr.z * br.z - wi.z * bi.z, ar.z);                   \
        oii.z = fmaf(sg, wr.z * bi.z + wi.z * br.z, ai.z);                   \
        orr.w = fmaf(sg, wr.w * br.w - wi.w * bi.w, ar.w);                   \
        oii.w = fmaf(sg, wr.w * bi.w + wi.w * br.w, ai.w);                   \
        *(float4*)((OR_) + 4 * l) = orr;                                     \
        *(float4*)((OI_) + 4 * l) = oii;                                     \
    }

__global__ __launch_bounds__(NTHREADS, 8) void mfcc_kernel(
    const float* __restrict__ x, const float* __restrict__ ws,
    float* __restrict__ out) {

    __shared__ __align__(16) float Are[4][256];
    __shared__ __align__(16) float Aim[4][256];
    __shared__ __align__(16) float Bre[4][256];
    __shared__ __align__(16) float Bim[4][256];
    __shared__ float melw_all[4][48];

    const int tid = threadIdx.x;
    const int w = tid >> 6;
    const int l = tid & 63;
    const int fid = blockIdx.x * 4 + w;
    const int b = fid / NF;
    const int f = fid - b * NF;
    const float* xp = x + (size_t)b * LL;
    const int start = f * HOP;

    float* AreW = Are[w];
    float* AimW = Aim[w];
    float* BreW = Bre[w];
    float* BimW = Bim[w];
    float* melw = melw_all[w];

    if (l < 48) melw[l] = 0.0f;

    // ---- pack: z[n] = y[2n]*w[2n] + i*y[2n+1]*w[2n+1], n = 4l..4l+3 ----
    float4 zr4 = make_float4(0.f, 0.f, 0.f, 0.f);
    float4 zi4 = make_float4(0.f, 0.f, 0.f, 0.f);
    if (l < 50) {                        // samples 8l..8l+7 (400 = 8*50 exactly)
        int g0 = start + 8 * l;
        float4 xa = *(const float4*)(xp + g0);
        float4 xc = *(const float4*)(xp + g0 + 4);
        float xm1 = (g0 > 0) ? xp[g0 - 1] : 0.0f;   // y[0]=x[0] at signal start
        float4 wa = *(const float4*)(ws + WS_WINDOW + 8 * l);
        float4 wb = *(const float4*)(ws + WS_WINDOW + 8 * l + 4);
        float y0 = xa.x - 0.97f * xm1;
        float y1 = xa.y - 0.97f * xa.x;
        float y2 = xa.z - 0.97f * xa.y;
        float y3 = xa.w - 0.97f * xa.z;
        float y4 = xc.x - 0.97f * xa.w;
        float y5 = xc.y - 0.97f * xc.x;
        float y6 = xc.z - 0.97f * xc.y;
        float y7 = xc.w - 0.97f * xc.z;
        zr4 = make_float4(y0 * wa.x, y2 * wa.z, y4 * wb.x, y6 * wb.z);
        zi4 = make_float4(y1 * wa.y, y3 * wa.w, y5 * wb.y, y7 * wb.w);
    }
    *(float4*)(AreW + 4 * l) = zr4;
    *(float4*)(AimW + 4 * l) = zi4;

    // ---- stage 0 (A->B): w=1; o=4l+r: j={2l,2l,2l+1,2l+1}, up={1,0,1,0} ----
    {
        float2 rl = *(const float2*)(AreW + 2 * l);
        float2 il = *(const float2*)(AimW + 2 * l);
        float2 rh = *(const float2*)(AreW + 128 + 2 * l);
        float2 ih = *(const float2*)(AimW + 128 + 2 * l);
        float4 orr = make_float4(rl.x + rh.x, rl.x - rh.x, rl.y + rh.y, rl.y - rh.y);
        float4 oii = make_float4(il.x + ih.x, il.x - ih.x, il.y + ih.y, il.y - ih.y);
        *(float4*)(BreW + 4 * l) = orr;
        *(float4*)(BimW + 4 * l) = oii;
    }

    // ---- stage 1 (B->A): w in {1,-i}; j={2l,2l+1,2l,2l+1}, up={1,1,0,0} ----
    {
        float2 rl = *(const float2*)(BreW + 2 * l);
        float2 il = *(const float2*)(BimW + 2 * l);
        float2 rh = *(const float2*)(BreW + 128 + 2 * l);
        float2 ih = *(const float2*)(BimW + 128 + 2 * l);
        float4 orr = make_float4(rl.x + rh.x, rl.y + ih.y, rl.x - rh.x, rl.y - ih.y);
        float4 oii = make_float4(il.x + ih.x, il.y - rh.y, il.x - ih.x, il.y + rh.y);
        *(float4*)(AreW + 4 * l) = orr;
        *(float4*)(AimW + 4 * l) = oii;
    }

    // ---- stages 2..7 ----
    STAGEV(2, AreW, AimW, BreW, BimW, WS_STW + 0 * 256);
    STAGEV(3, BreW, BimW, AreW, AimW, WS_STW + 1 * 256);
    STAGEV(4, AreW, AimW, BreW, BimW, WS_STW + 2 * 256);
    STAGEV(5, BreW, BimW, AreW, AimW, WS_STW + 3 * 256);
    STAGEV(6, AreW, AimW, BreW, BimW, WS_STW + 4 * 256);
    STAGEV(7, BreW, BimW, AreW, AimW, WS_STW + 5 * 256);   // result in A

    // ---- untangle to rfft magnitude, k = 4l..4l+3 (bin 256 has no mel weight) ----
    float4 zrN = *(const float4*)(AreW + 4 * l);
    float4 ziN = *(const float4*)(AimW + 4 * l);
    float4 wc  = *(const float4*)(ws + WS_TW512C + 4 * l);
    float4 wsn = *(const float4*)(ws + WS_TW512S + 4 * l);
    float mg[4];
    #pragma unroll
    for (int r = 0; r < 4; r++) {
        int k = 4 * l + r;
        int k2 = (256 - k) & 255;
        float a  = (&zrN.x)[r];
        float bb = (&ziN.x)[r];
        float c  = AreW[k2];
        float d  = AimW[k2];
        float Pr = a + c, Pi = bb - d;
        float Qr = a - c, Qi = bb + d;
        float wr_ = (&wc.x)[r];
        float wi_ = (&wsn.x)[r];
        float Xr = 0.5f * (Pr + wi_ * Qr + wr_ * Qi);
        float Xi = 0.5f * (Pi + wi_ * Qi - wr_ * Qr);
        mg[r] = sqrtf(Xr * Xr + Xi * Xi);
    }

    // ---- mel: per-k scatter into per-wave buffer (<=2 filters per bin) ----
    const float4* msc = (const float4*)(ws + WS_MELSC);
    #pragma unroll
    for (int r = 0; r < 4; r++) {
        float4 t = msc[4 * l + r];
        int m = (int)t.z;                 // rising filter index, 0..40
        atomicAdd(&melw[1 + m], t.x * mg[r]);   // row m     (idx 41 = trash)
        atomicAdd(&melw[m],     t.y * mg[r]);   // row m-1   (idx 0  = trash)
    }

    // ---- log ----
    float lmv = 0.0f;
    if (l < 40) lmv = logf(melw[1 + l] + 1e-20f);

    // ---- fused DCT+deltas: out[i] = sum_n MT[n][i] * lm[n] ----
    float acc = 0.0f;
    const float* mt = ws + WS_MT;
    int ii = (l < 39) ? l : 0;
    #pragma unroll 8
    for (int n = 0; n < 40; n++) {
        float lmn = __shfl(lmv, n, 64);
        acc = fmaf(mt[n * 39 + ii], lmn, acc);
    }
    if (l < 39) out[(size_t)fid * 39 + l] = acc;
}

// ---------------------------------------------------------------------------
extern "C" void kernel_launch(void* const* d_in, const int* in_sizes, int n_in,
                              void* d_out, int out_size, void* d_ws, size_t ws_size,
                              hipStream_t stream) {
    const float* x = (const float*)d_in[0];
    float* ws = (float*)d_ws;
    float* out = (float*)d_out;

    init_tables<<<1, 256, 0, stream>>>(ws);
    mfcc_kernel<<<(BB * NF) / 4, NTHREADS, 0, stream>>>(x, ws, out);
}

// Round 4
// 295.451 us; speedup vs baseline: 4.0966x; 1.1663x over previous
//
#include <hip/hip_runtime.h>
#include <cmath>

#define SRATE 16000
#define WIN   400
#define HOP   160
#define NFFT  512
#define NBIN  257          // NFFT/2+1
#define NMELS 40
#define NMFCC 13
#define BB    64
#define LL    160000
#define NF    998          // (L-WIN)/HOP + 1

#define PI_D 3.14159265358979323846

// workspace layout (floats)
#define WS_WINDOW 0                    // 400
#define WS_W1     400                  // 64 x float2 = 128   (W_256^l)
#define WS_STW    528                  // 6 stages x 64 x float2 = 768
#define WS_UNTC   1296                 // 64 x float4 = 256 (permuted untangle cos)
#define WS_UNTS   1552                 // 64 x float4 = 256 (permuted untangle -sin)
#define WS_MELT   1808                 // 4 slots x 64 x float4 = 1024 (permuted mel scatter)
#define WS_MT     2832                 // 40 x 39 = 1560 (fused DCT+delta, [n][i])
#define WS_TOTAL  (WS_MT + 1560)       // 4392 floats

__device__ __forceinline__ int brev6(int v) { return (int)(__brev((unsigned)v) >> 26); }

// ---------------------------------------------------------------------------
// Init kernel: recompute constant tables every launch (ws is re-poisoned).
// ---------------------------------------------------------------------------
__global__ void init_tables(float* __restrict__ ws) {
    __shared__ double bins[NMELS + 2];
    const int tid = threadIdx.x;

    // Hamming window (periodic)
    for (int i = tid; i < WIN; i += 256)
        ws[WS_WINDOW + i] = (float)(0.54 - 0.46 * cos(2.0 * PI_D * (double)i / (double)WIN));

    // W1[l] = e^{-2*pi*i*l/256}
    if (tid < 64) {
        double ang = -2.0 * PI_D * (double)tid / 256.0;
        ws[WS_W1 + 2 * tid]     = (float)cos(ang);
        ws[WS_W1 + 2 * tid + 1] = (float)sin(ang);
    }

    // cross-lane DIF stage twiddles: stage st (h = 32>>st), lane l:
    //   (l & h) ? e^{-i*pi*(l&(h-1))/h} : 1
    for (int i = tid; i < 6 * 64; i += 256) {
        int st = i >> 6, lane = i & 63;
        int h = 32 >> st;
        double cr = 1.0, ci = 0.0;
        if (lane & h) {
            double ang = -PI_D * (double)(lane & (h - 1)) / (double)h;
            cr = cos(ang); ci = sin(ang);
        }
        ws[WS_STW + st * 128 + 2 * lane]     = (float)cr;
        ws[WS_STW + st * 128 + 2 * lane + 1] = (float)ci;
    }

    // permuted untangle twiddles: lane l slot k1 -> m = k1 + 4*bitrev6(l)
    if (tid < 256) {
        int lane = tid >> 2, k1 = tid & 3;
        int m = k1 + 4 * brev6(lane);
        double ang = 2.0 * PI_D * (double)m / 512.0;
        ws[WS_UNTC + 4 * lane + k1] = (float)cos(ang);
        ws[WS_UNTS + 4 * lane + k1] = (float)(-sin(ang));
    }

    // mel bin edges
    if (tid < NMELS + 2) {
        double high_mel = 2595.0 * log10(1.0 + ((double)SRATE / 2.0) / 700.0);
        double step = high_mel / (double)(NMELS + 1);
        double mel = (tid == NMELS + 1) ? high_mel : (double)tid * step;
        double hz = 700.0 * (pow(10.0, mel / 2595.0) - 1.0);
        bins[tid] = floor((double)(NFFT + 1) * hz / (double)SRATE);
    }
    __syncthreads();

    // permuted mel scatter table: slot-major [k1][lane] float4
    if (tid < 256) {
        int k1 = tid >> 6, lane = tid & 63;
        int k = k1 + 4 * brev6(lane);
        int r1 = 0;
        while (r1 < NMELS + 1 &&
               !((double)k >= bins[r1] && (double)k < bins[r1 + 1])) r1++;
        if (r1 > NMELS) r1 = NMELS;
        double lo = bins[r1], hi = bins[r1 + 1];
        double den = (hi > lo) ? (hi - lo) : 1.0;
        float* e = ws + WS_MELT + k1 * 256 + lane * 4;
        e[0] = (float)(((double)k - lo) / den);   // rising  -> row r1   (melw[1+r1])
        e[1] = (float)((hi - (double)k) / den);   // falling -> row r1-1 (melw[r1])
        e[2] = (float)r1;
        e[3] = 0.0f;
    }

    // fused DCT + delta matrix, [n][i] layout: MT[n*39 + i]
    for (int t = tid; t < 40 * 39; t += 256) {
        int n = t / 39, i = t % 39;
        auto dctf = [&](int c) -> double {
            if (c < 0 || c > 39) return 0.0;
            double sc = (c == 0) ? sqrt(1.0 / 40.0) : sqrt(2.0 / 40.0);
            return sc * cos(PI_D * (double)c * (2.0 * n + 1.0) / 80.0);
        };
        auto d1f = [&](int c) -> double {
            if (c < 1 || c > 38) return 0.0;
            return 0.5 * (dctf(c + 1) - dctf(c - 1));
        };
        double v;
        if (i < 13)       v = dctf(i);
        else if (i < 26)  v = d1f(i - 13);
        else { int c = i - 26; v = (c >= 1 && c <= 38) ? 0.5 * (d1f(c + 1) - d1f(c - 1)) : 0.0; }
        ws[WS_MT + t] = (float)v;
    }
}

// ---------------------------------------------------------------------------
// Main kernel: one WAVE per frame; register FFT (4-step 4x64) via shuffles.
// ---------------------------------------------------------------------------
#define NTHREADS 256

__global__ __launch_bounds__(NTHREADS, 6) void mfcc_kernel(
    const float* __restrict__ x, const float* __restrict__ ws,
    float* __restrict__ out) {

    __shared__ float melw_all[4][48];
    __shared__ __align__(16) float lm_all[4][44];

    const int tid = threadIdx.x;
    const int w = tid >> 6;
    const int l = tid & 63;
    const int fid = blockIdx.x * 4 + w;
    const int b = fid / NF;
    const int f = fid - b * NF;
    const float* xp = x + (size_t)b * LL;
    const int start = f * HOP;
    float* melw = melw_all[w];
    float* lmarr = lm_all[w];

    if (l < 48) melw[l] = 0.0f;

    // ---- pack: lane l holds z[l + 64*a], a=0..3 (pre-emphasis + window) ----
    float z0r, z0i, z1r, z1i, z2r, z2i, z3r, z3i;
#define PACK(A, ZR, ZI)                                               \
    {                                                                 \
        float xr = 0.0f, xi = 0.0f;                                   \
        int n2pos = 2 * l + 128 * (A);                                \
        if (n2pos < WIN) {                                            \
            int g = start + n2pos;                                    \
            float2 xv = *(const float2*)(xp + g);                     \
            float xprev = (g > 0) ? xp[g - 1] : 0.0f;                 \
            float2 wv = *(const float2*)(ws + WS_WINDOW + n2pos);     \
            xr = (xv.x - 0.97f * xprev) * wv.x;                       \
            xi = (xv.y - 0.97f * xv.x) * wv.y;                        \
        }                                                             \
        ZR = xr; ZI = xi;                                             \
    }
    PACK(0, z0r, z0i)
    PACK(1, z1r, z1i)
    PACK(2, z2r, z2i)
    PACK(3, z3r, z3i)
#undef PACK

    // ---- in-register radix-4 over n1 (W4^1 = -i) ----
    {
        float t0r = z0r + z2r, t0i = z0i + z2i;
        float t1r = z0r - z2r, t1i = z0i - z2i;
        float t2r = z1r + z3r, t2i = z1i + z3i;
        float t3r = z1r - z3r, t3i = z1i - z3i;
        z0r = t0r + t2r; z0i = t0i + t2i;
        z1r = t1r + t3i; z1i = t1i - t3r;
        z2r = t0r - t2r; z2i = t0i - t2i;
        z3r = t1r - t3i; z3i = t1i + t3r;
    }

    // ---- twiddle: slot k1 *= W_256^{l*k1} ----
    {
        float2 w1 = *(const float2*)(ws + WS_W1 + 2 * l);
        float w2r = w1.x * w1.x - w1.y * w1.y, w2i = 2.0f * w1.x * w1.y;
        float w3r = w2r * w1.x - w2i * w1.y,   w3i = w2r * w1.y + w2i * w1.x;
        float tr;
        tr  = z1r * w1.x - z1i * w1.y; z1i = z1r * w1.y + z1i * w1.x; z1r = tr;
        tr  = z2r * w2r  - z2i * w2i;  z2i = z2r * w2i  + z2i * w2r;  z2r = tr;
        tr  = z3r * w3r  - z3i * w3i;  z3i = z3r * w3i  + z3i * w3r;  z3r = tr;
    }

    // ---- 6 cross-lane DIF stages via shfl_xor (output bit-reversed) ----
#define BFLY(ZR, ZI, H, TWR, TWI, SGN, LAST)                          \
    {                                                                 \
        float pr = __shfl_xor(ZR, (H), 64);                           \
        float pi = __shfl_xor(ZI, (H), 64);                           \
        float ar = fmaf((SGN), ZR, pr);                               \
        float ai = fmaf((SGN), ZI, pi);                               \
        if (LAST) { ZR = ar; ZI = ai; }                               \
        else { ZR = ar * (TWR) - ai * (TWI);                          \
               ZI = ar * (TWI) + ai * (TWR); }                        \
    }
#define CLSTAGE(H, ST, LAST)                                          \
    {                                                                 \
        float sgn = (l & (H)) ? -1.0f : 1.0f;                         \
        float twr = 1.0f, twi = 0.0f;                                 \
        if (!(LAST)) {                                                \
            float2 t = *(const float2*)(ws + WS_STW + (ST) * 128 + 2 * l); \
            twr = t.x; twi = t.y;                                     \
        }                                                             \
        BFLY(z0r, z0i, H, twr, twi, sgn, LAST)                        \
        BFLY(z1r, z1i, H, twr, twi, sgn, LAST)                        \
        BFLY(z2r, z2i, H, twr, twi, sgn, LAST)                        \
        BFLY(z3r, z3i, H, twr, twi, sgn, LAST)                        \
    }
    CLSTAGE(32, 0, false)
    CLSTAGE(16, 1, false)
    CLSTAGE(8,  2, false)
    CLSTAGE(4,  3, false)
    CLSTAGE(2,  4, false)
    CLSTAGE(1,  5, true)     // W_2^0 = 1: no twiddle
#undef CLSTAGE
#undef BFLY

    // lane l slot k1 now holds Z[m], m = k1 + 4*bitrev6(l)

    // ---- rfft untangle: partner Z[(256-m)&255] ----
    float p1r = __shfl(z3r, 63 - l, 64), p1i = __shfl(z3i, 63 - l, 64);
    float p2r = __shfl(z2r, 63 - l, 64), p2i = __shfl(z2i, 63 - l, 64);
    float p3r = __shfl(z1r, 63 - l, 64), p3i = __shfl(z1i, 63 - l, 64);
    int r2 = brev6(l);
    int q  = brev6((64 - r2) & 63);
    float p0r = __shfl(z0r, q, 64), p0i = __shfl(z0i, q, 64);

    float4 uc = *(const float4*)(ws + WS_UNTC + 4 * l);
    float4 us = *(const float4*)(ws + WS_UNTS + 4 * l);

    float mg0, mg1, mg2, mg3;
#define UNT(A, Bv, C, D, WR, WI, MG)                                  \
    {                                                                 \
        float Pr = (A) + (C), Pi = (Bv) - (D);                        \
        float Qr = (A) - (C), Qi = (Bv) + (D);                        \
        float Xr = 0.5f * (Pr + (WI) * Qr + (WR) * Qi);               \
        float Xi = 0.5f * (Pi + (WI) * Qi - (WR) * Qr);               \
        MG = sqrtf(Xr * Xr + Xi * Xi);                                \
    }
    UNT(z0r, z0i, p0r, p0i, uc.x, us.x, mg0)
    UNT(z1r, z1i, p1r, p1i, uc.y, us.y, mg1)
    UNT(z2r, z2i, p2r, p2i, uc.z, us.z, mg2)
    UNT(z3r, z3i, p3r, p3i, uc.w, us.w, mg3)
#undef UNT

    // ---- mel scatter (pre-permuted table), per-wave LDS atomics ----
    {
        const float4* mlt = (const float4*)(ws + WS_MELT);
        float4 t0 = mlt[0 * 64 + l];
        float4 t1 = mlt[1 * 64 + l];
        float4 t2 = mlt[2 * 64 + l];
        float4 t3 = mlt[3 * 64 + l];
        int r;
        r = (int)t0.z; atomicAdd(&melw[1 + r], t0.x * mg0); atomicAdd(&melw[r], t0.y * mg0);
        r = (int)t1.z; atomicAdd(&melw[1 + r], t1.x * mg1); atomicAdd(&melw[r], t1.y * mg1);
        r = (int)t2.z; atomicAdd(&melw[1 + r], t2.x * mg2); atomicAdd(&melw[r], t2.y * mg2);
        r = (int)t3.z; atomicAdd(&melw[1 + r], t3.x * mg3); atomicAdd(&melw[r], t3.y * mg3);
    }
    __builtin_amdgcn_wave_barrier();

    // ---- log, stage lm into per-wave LDS for b128 broadcast ----
    if (l < NMELS) lmarr[l] = logf(melw[1 + l] + 1e-20f);
    __builtin_amdgcn_wave_barrier();

    // ---- fused DCT+deltas matvec ----
    float acc = 0.0f;
    const float* mt = ws + WS_MT;
    int ii = (l < 39) ? l : 0;
    #pragma unroll
    for (int g = 0; g < 10; g++) {
        float4 lm4 = *(const float4*)(lmarr + 4 * g);   // broadcast read
        acc = fmaf(mt[(4 * g + 0) * 39 + ii], lm4.x, acc);
        acc = fmaf(mt[(4 * g + 1) * 39 + ii], lm4.y, acc);
        acc = fmaf(mt[(4 * g + 2) * 39 + ii], lm4.z, acc);
        acc = fmaf(mt[(4 * g + 3) * 39 + ii], lm4.w, acc);
    }
    if (l < 39) out[(size_t)fid * 39 + l] = acc;
}

// ---------------------------------------------------------------------------
extern "C" void kernel_launch(void* const* d_in, const int* in_sizes, int n_in,
                              void* d_out, int out_size, void* d_ws, size_t ws_size,
                              hipStream_t stream) {
    const float* x = (const float*)d_in[0];
    float* ws = (float*)d_ws;
    float* out = (float*)d_out;

    init_tables<<<1, 256, 0, stream>>>(ws);
    mfcc_kernel<<<(BB * NF) / 4, NTHREADS, 0, stream>>>(x, ws, out);
}